// Round 6
// baseline (137.335 us; speedup 1.0000x reference)
//
#include <hip/hip_runtime.h>

// MechanicsPINN: residual = EI*biharm(f) + GC*lap(f) + KC*f - P,
// f = MLP(x) 2->256->512->1024->65536, B=64, grid 256x256. All inputs fp32.
// Round 6: main GEMM (M=64,N=65536,K=1024) bf16 MFMA, BARRIER-FREE.
//  - wave-private DMA pipeline: each wave stages only its own 32x16 W-subtile
//    (2KB) -> no inter-wave sharing -> no __syncthreads/s_barrier at all.
//  - 3 statically-named LDS buffers + hand-unrolled x3 loop -> compiler alias
//    analysis emits precise counted vmcnt (never a full drain).
//  - A-frag prefetch issued BEFORE the stage DMAs each step, so the MFMA's
//    A-wait (FIFO vmcnt) leaves the staging queue in flight.
//  - col-rotation swizzle q'=(q+(k>>3))&3 at global source, inverted at read
//    -> 2-way (free) LDS banks.

#define BATCH 64
#define NPIX 65536

typedef __attribute__((ext_vector_type(8))) short short8_t;  // bf16 x8 (4 VGPR)
typedef __attribute__((ext_vector_type(4))) float f32x4;

__device__ __forceinline__ short f2bf(float x) {  // fp32 -> bf16 RNE
    unsigned u = __float_as_uint(x);
    unsigned r = (u + 0x7fffu + ((u >> 16) & 1u)) >> 16;
    return (short)r;
}

// ---------------- Layer 1: h1 = relu(x @ W1 + b1), K=2 ----------------
__global__ void k_l1(const float* __restrict__ x, const float* __restrict__ W1,
                     const float* __restrict__ b1, float* __restrict__ h1) {
    int gid = blockIdx.x * 256 + threadIdx.x;   // 64*256 threads
    int m = gid >> 8, n = gid & 255;
    float v = x[m * 2 + 0] * W1[n] + x[m * 2 + 1] * W1[256 + n] + b1[n];
    h1[gid] = v > 0.f ? v : 0.f;
}

// ------------- Generic small layer: out = relu(A @ W + b) -------------
__global__ void k_layer(const float* __restrict__ A, const float* __restrict__ Wt,
                        const float* __restrict__ bias, float* __restrict__ out,
                        short* __restrict__ out_bf, int K, int N) {
    __shared__ float As[16][64];
    __shared__ float Ws[64][16];
    int tid = threadIdx.x;
    int tn = tid & 15, tm = tid >> 4;
    int n0 = blockIdx.x * 16, m0 = blockIdx.y * 16;
    float acc = 0.f;
    for (int k0 = 0; k0 < K; k0 += 64) {
#pragma unroll
        for (int j = 0; j < 4; ++j) {          // stage A 16x64
            int e = j * 256 + tid;
            As[e >> 6][e & 63] = A[(m0 + (e >> 6)) * K + k0 + (e & 63)];
        }
#pragma unroll
        for (int j = 0; j < 4; ++j) {          // stage W 64x16
            int e = j * 256 + tid;
            Ws[e >> 4][e & 15] = Wt[(k0 + (e >> 4)) * N + n0 + (e & 15)];
        }
        __syncthreads();
#pragma unroll
        for (int k = 0; k < 64; ++k)
            acc += As[tm][k] * Ws[k][tn];
        __syncthreads();
    }
    acc += bias[n0 + tn];
    acc = acc > 0.f ? acc : 0.f;               // relu
    if (out_bf)
        out_bf[(m0 + tm) * N + n0 + tn] = f2bf(acc);
    else
        out[(m0 + tm) * N + n0 + tn] = acc;
}

// ---------- Main GEMM: f = h3b @ W4 + b4 (bf16 MFMA, M=64,N=65536,K=1024) ----
// 256 threads = 4 waves; block covers 64 n-cols; wave w owns cols
// n0 + w*16 .. +15, all 64 m rows. Fully wave-independent: no barriers.
__global__ __launch_bounds__(256, 4) void k_gemm_mfma(
        const short* __restrict__ A,     // h3 bf16 [64][1024]
        const float* __restrict__ W,     // W4 fp32 [1024][65536]
        const float* __restrict__ bias,  // [65536]
        float* __restrict__ f) {         // [64][65536]
    // wave-private 32k x 16col fp32 subtiles, 3 static buffers (alias-precise)
    __shared__ float B0[4][512];
    __shared__ float B1[4][512];
    __shared__ float B2[4][512];
    const int tid = threadIdx.x;
    const int lane = tid & 63;
    const int w = tid >> 6;
    const int lr = lane & 15;
    const int g = lane >> 4;             // k-group 0..3
    const int n0w = blockIdx.x * 64 + w * 16;   // this wave's first col

    f32x4 acc[4] = {{0.f, 0.f, 0.f, 0.f}, {0.f, 0.f, 0.f, 0.f},
                    {0.f, 0.f, 0.f, 0.f}, {0.f, 0.f, 0.f, 0.f}};

    // A-frag (mt,s): elem j = A[(mt*16+lr)*1024 + s*32 + g*8 + j], 16B loads
    const short* ap = A + lr * 1024 + g * 8;

    float* myB0 = &B0[w][0];
    float* myB1 = &B1[w][0];
    float* myB2 = &B2[w][0];

    // stage this wave's 32x16 fp32 subtile (128 chunks of 16B, 2/lane).
    // chunk c: k=c>>2, slot q=c&3; global col-group qsw=(q+(k>>3))&3 (rotation
    // swizzle keyed on k bit3/bit4 = g of the eventual reader).
    auto stage = [&](float* buf, int k0) {
#pragma unroll
        for (int i = 0; i < 2; ++i) {
            int c = i * 64 + lane;
            int k = c >> 2, q = c & 3;
            int qsw = (q + (k >> 3)) & 3;
            const float* src = W + (size_t)(k0 + k) * NPIX + n0w + qsw * 4;
            __builtin_amdgcn_global_load_lds(
                (const __attribute__((address_space(1))) void*)src,
                (__attribute__((address_space(3))) void*)((char*)buf + i * 1024),
                16, 0, 0);
        }
    };

    short8_t aC[4], aN[4];

    stage(myB0, 0);
    stage(myB1, 32);
#pragma unroll
    for (int mt = 0; mt < 4; ++mt)
        aC[mt] = *(const short8_t*)(ap + mt * 16384);          // s = 0

    // B-frag read: col lr at k=g*8+j lives at slot q=((lr>>2)-g)&3:
    // float idx = k*16 + q*4 + (lr&3) = g*128 + j*16 + boff
    const int boff = ((((lr >> 2) - g) & 3) << 2) + (lr & 3);

    auto compute = [&](const float* buf) {
        const float* wb = buf + g * 128 + boff;
        short8_t bf;
#pragma unroll
        for (int j = 0; j < 8; ++j)
            bf[j] = f2bf(wb[j * 16]);
#pragma unroll
        for (int mt = 0; mt < 4; ++mt)
            acc[mt] = __builtin_amdgcn_mfma_f32_16x16x32_bf16(aC[mt], bf, acc[mt], 0, 0, 0);
    };

    // step s: A-prefetch(s+1) FIRST, then stage(s+2), then compute(s).
    auto step = [&](const float* cur, float* stg, int s, bool do_stage, bool do_a) {
        if (do_a) {
#pragma unroll
            for (int mt = 0; mt < 4; ++mt)
                aN[mt] = *(const short8_t*)(ap + mt * 16384 + (s + 1) * 32);
        }
        if (do_stage) stage(stg, (s + 2) * 32);
        compute(cur);
        if (do_a) {
#pragma unroll
            for (int mt = 0; mt < 4; ++mt) aC[mt] = aN[mt];
        }
    };

    for (int t = 0; t < 10; ++t) {
        int s = t * 3;
        step(myB0, myB2, s + 0, true, true);
        step(myB1, myB0, s + 1, true, true);
        step(myB2, myB1, s + 2, true, true);
    }
    step(myB0, myB2, 30, false, true);
    step(myB1, myB2, 31, false, false);

    // C/D layout: col = lane&15, row = (lane>>4)*4 + reg
    const int col = n0w + lr;
    float bb = bias[col];
#pragma unroll
    for (int mt = 0; mt < 4; ++mt) {
        int rowb = mt * 16 + g * 4;
#pragma unroll
        for (int r = 0; r < 4; ++r)
            f[(size_t)(rowb + r) * NPIX + col] = acc[mt][r] + bb;
    }
}

// --------------------------- Stencil ---------------------------
// residual = biharm + lap + f - P; reflect-1 index reflection.
#define ROWS 16
__device__ __forceinline__ int rfl(int i) {
    return i < 0 ? -i : (i > 255 ? 510 - i : i);
}
__global__ void k_stencil(const float* __restrict__ f, const float* __restrict__ P,
                          float* __restrict__ out) {
    __shared__ float fs[ROWS + 4][256];
    int x = threadIdx.x;
    int y0 = blockIdx.x * ROWS;
    int b = blockIdx.y;
    const float* fb = f + (size_t)b * NPIX;
    for (int t = 0; t < ROWS + 4; ++t) {
        int gy = rfl(y0 - 2 + t);
        fs[t][x] = fb[gy * 256 + x];
    }
    __syncthreads();

    int xm = x == 0 ? 1 : x - 1;
    int xp = x == 255 ? 254 : x + 1;

    auto lapAt = [&](int j, int i) {
        int s = j - y0 + 2;
        int sm = rfl(j - 1) - y0 + 2;
        int sp = rfl(j + 1) - y0 + 2;
        int im = i == 0 ? 1 : i - 1;
        int ip = i == 255 ? 254 : i + 1;
        float c = fs[s][i];
        return (fs[sm][i] - 2.f * c + fs[sp][i]) + (fs[s][im] - 2.f * c + fs[s][ip]);
    };

    for (int r = 0; r < ROWS; ++r) {
        int y = y0 + r;
        float lc = lapAt(y, x);
        float lym = lapAt(rfl(y - 1), x);
        float lyp = lapAt(rfl(y + 1), x);
        float lxm = lapAt(y, xm);
        float lxp = lapAt(y, xp);
        float bih = (lym - 2.f * lc + lyp) + (lxm - 2.f * lc + lxp);
        float fc = fs[r + 2][x];
        size_t idx = (size_t)b * NPIX + y * 256 + x;
        out[idx] = bih + lc + fc - P[idx];
    }
}

extern "C" void kernel_launch(void* const* d_in, const int* in_sizes, int n_in,
                              void* d_out, int out_size, void* d_ws, size_t ws_size,
                              hipStream_t stream) {
    const float* x  = (const float*)d_in[0];
    const float* P  = (const float*)d_in[1];
    const float* W1 = (const float*)d_in[2];
    const float* b1 = (const float*)d_in[3];
    const float* W2 = (const float*)d_in[4];
    const float* b2 = (const float*)d_in[5];
    const float* W3 = (const float*)d_in[6];
    const float* b3 = (const float*)d_in[7];
    const float* W4 = (const float*)d_in[8];
    const float* b4 = (const float*)d_in[9];
    float* out = (float*)d_out;

    char* ws = (char*)d_ws;
    float* h1  = (float*)(ws);                      // 64*256*4  = 64 KB
    float* h2  = (float*)(ws + (64 << 10));         // 64*512*4  = 128 KB
    short* h3b = (short*)(ws + (192 << 10));        // 64*1024*2 = 128 KB (bf16)
    float* f   = (float*)(ws + (320 << 10));        // 64*65536*4 = 16 MB

    k_l1<<<64, 256, 0, stream>>>(x, W1, b1, h1);
    k_layer<<<dim3(512 / 16, 4), 256, 0, stream>>>(h1, W2, b2, h2, nullptr, 256, 512);
    k_layer<<<dim3(1024 / 16, 4), 256, 0, stream>>>(h2, W3, b3, nullptr, h3b, 512, 1024);
    k_gemm_mfma<<<NPIX / 64, 256, 0, stream>>>(h3b, W4, b4, f);
    k_stencil<<<dim3(256 / ROWS, BATCH), 256, 0, stream>>>(f, P, out);
}

// Round 8
// 93.197 us; speedup vs baseline: 1.4736x; 1.4736x over previous
//
#include <hip/hip_runtime.h>

// MechanicsPINN: residual = EI*biharm(f) + GC*lap(f) + KC*f - P,
// f = MLP(x) 2->256->512->1024->65536, B=64, grid 256x256. All inputs fp32.
// Round 8: R7 structure (zero-barrier reg-staged bf16 MFMA GEMM) + the missing
// wavefront-scope LDS fences. Cross-lane LDS hand-off (lwrite by lane Y ->
// read by lane X) needs (a) compiler ordering, (b) lgkmcnt drain -- NOT a
// vmcnt drain. s_waitcnt lgkmcnt(0) + "memory" clobber gives both; the
// global-load queue (W tiles + A frags) stays in flight across all 32 K-steps.

#define BATCH 64
#define NPIX 65536

typedef __attribute__((ext_vector_type(8))) short short8_t;  // bf16 x8 (4 VGPR)
typedef __attribute__((ext_vector_type(4))) float f32x4;

#define LDS_FENCE()   asm volatile("s_waitcnt lgkmcnt(0)" ::: "memory")
#define MEM_ORDER()   asm volatile("" ::: "memory")

__device__ __forceinline__ short f2bf(float x) {  // fp32 -> bf16 RNE
    unsigned u = __float_as_uint(x);
    unsigned r = (u + 0x7fffu + ((u >> 16) & 1u)) >> 16;
    return (short)r;
}

// -------- Fused layers 1+2: h2 = relu(relu(x@W1+b1) @ W2 + b2) --------
__global__ void k_layer12(const float* __restrict__ x, const float* __restrict__ W1,
                          const float* __restrict__ b1, const float* __restrict__ W2,
                          const float* __restrict__ b2, float* __restrict__ h2) {
    __shared__ float As[16][64];
    __shared__ float Ws[64][16];
    int tid = threadIdx.x;
    int tn = tid & 15, tm = tid >> 4;
    int n0 = blockIdx.x * 16, m0 = blockIdx.y * 16;
    float acc = 0.f;
    for (int k0 = 0; k0 < 256; k0 += 64) {
#pragma unroll
        for (int j = 0; j < 4; ++j) {          // build h1 16x64 tile on the fly
            int e = j * 256 + tid;
            int m = m0 + (e >> 6), kk = k0 + (e & 63);
            float v = x[m * 2 + 0] * W1[kk] + x[m * 2 + 1] * W1[256 + kk] + b1[kk];
            As[e >> 6][e & 63] = v > 0.f ? v : 0.f;
        }
#pragma unroll
        for (int j = 0; j < 4; ++j) {          // stage W2 64x16
            int e = j * 256 + tid;
            Ws[e >> 4][e & 15] = W2[(k0 + (e >> 4)) * 512 + n0 + (e & 15)];
        }
        __syncthreads();
#pragma unroll
        for (int k = 0; k < 64; ++k)
            acc += As[tm][k] * Ws[k][tn];
        __syncthreads();
    }
    acc += b2[n0 + tn];
    acc = acc > 0.f ? acc : 0.f;
    h2[(m0 + tm) * 512 + n0 + tn] = acc;
}

// -------- Layer 3: h3b(bf16) = relu(h2 @ W3 + b3), K=512, N=1024 --------
__global__ void k_layer3(const float* __restrict__ A, const float* __restrict__ Wt,
                         const float* __restrict__ bias, short* __restrict__ out_bf) {
    __shared__ float As[16][64];
    __shared__ float Ws[64][16];
    int tid = threadIdx.x;
    int tn = tid & 15, tm = tid >> 4;
    int n0 = blockIdx.x * 16, m0 = blockIdx.y * 16;
    float acc = 0.f;
    for (int k0 = 0; k0 < 512; k0 += 64) {
#pragma unroll
        for (int j = 0; j < 4; ++j) {
            int e = j * 256 + tid;
            As[e >> 6][e & 63] = A[(m0 + (e >> 6)) * 512 + k0 + (e & 63)];
        }
#pragma unroll
        for (int j = 0; j < 4; ++j) {
            int e = j * 256 + tid;
            Ws[e >> 4][e & 15] = Wt[(k0 + (e >> 4)) * 1024 + n0 + (e & 15)];
        }
        __syncthreads();
#pragma unroll
        for (int k = 0; k < 64; ++k)
            acc += As[tm][k] * Ws[k][tn];
        __syncthreads();
    }
    acc += bias[n0 + tn];
    acc = acc > 0.f ? acc : 0.f;
    out_bf[(m0 + tm) * 1024 + n0 + tn] = f2bf(acc);
}

// ---------- Main GEMM: f = h3b @ W4 + b4 (bf16 MFMA, M=64,N=65536,K=1024) ----
// One wave per block. Wave: 64 cols x 64 m = 16 MFMA per 32-k step.
__global__ __launch_bounds__(64) void k_gemm_mfma(
        const short* __restrict__ A,     // h3 bf16 [64][1024]
        const float* __restrict__ W,     // W4 fp32 [1024][65536]
        const float* __restrict__ bias,  // [65536]
        float* __restrict__ f) {         // [64][65536]
    __shared__ float Bl[32 * 64];        // 8KB wave-private [k][col], swizzled
    const int lane = threadIdx.x;
    const int lr = lane & 15;
    const int g = lane >> 4;             // k-group 0..3
    const int n0w = blockIdx.x * 64;

    f32x4 acc[4][4];                     // [m-tile][n-tile]
#pragma unroll
    for (int a = 0; a < 4; ++a)
#pragma unroll
        for (int b = 0; b < 4; ++b)
            acc[a][b] = {0.f, 0.f, 0.f, 0.f};

    const short* ap = A + lr * 1024 + g * 8;

    f32x4 R[8];                          // staging regs: 32x64 tile, 32 VGPR
    // load chunk: instr i covers k-rows i*4..i*4+3, 256B contiguous per row
    auto gload = [&](int k0) {
#pragma unroll
        for (int i = 0; i < 8; ++i) {
            int k = i * 4 + (lane >> 4);
            R[i] = *(const f32x4*)(W + (size_t)(k0 + k) * NPIX + n0w + (lane & 15) * 4);
        }
    };
    // LDS element (k,col) at float idx k*64 + (col ^ ((k>>3)<<4))
    auto lwrite = [&]() {
#pragma unroll
        for (int i = 0; i < 8; ++i) {
            int k = i * 4 + (lane >> 4);
            int cc = ((lane & 15) * 4) ^ (((i >> 1) & 3) << 4);
            *(f32x4*)&Bl[k * 64 + cc] = R[i];
        }
    };

    short8_t aC[4], aN[4];

    // prologue: tile0 -> LDS; tile1 + A(0),A(1) in flight
    gload(0);
#pragma unroll
    for (int mt = 0; mt < 4; ++mt)
        aC[mt] = *(const short8_t*)(ap + mt * 16384);
    lwrite();
    gload(32);
#pragma unroll
    for (int mt = 0; mt < 4; ++mt)
        aN[mt] = *(const short8_t*)(ap + mt * 16384 + 32);
    LDS_FENCE();                         // tile0 writes visible to all lanes

    for (int s = 0; s < 32; ++s) {
        // compute(s): 4 B-frags from LDS, 16 MFMA
#pragma unroll
        for (int t = 0; t < 4; ++t) {
            const int csw = (t * 16 + lr) ^ (g << 4);
            short8_t bf;
#pragma unroll
            for (int j = 0; j < 8; ++j)
                bf[j] = f2bf(Bl[(g * 8 + j) * 64 + csw]);
#pragma unroll
            for (int mt = 0; mt < 4; ++mt)
                acc[mt][t] = __builtin_amdgcn_mfma_f32_16x16x32_bf16(aC[mt], bf, acc[mt][t], 0, 0, 0);
        }
        MEM_ORDER();                     // keep lwrite stores below the reads
        if (s < 31) {
            lwrite();                            // waits R(s+1) only (counted vmcnt)
            LDS_FENCE();                         // lgkm drain only; vmem stays in flight
            if (s < 30) gload((s + 2) * 32);     // keep ~8KB in flight
#pragma unroll
            for (int mt = 0; mt < 4; ++mt) aC[mt] = aN[mt];  // waits A(s+1)
            if (s < 30) {
#pragma unroll
                for (int mt = 0; mt < 4; ++mt)
                    aN[mt] = *(const short8_t*)(ap + mt * 16384 + (s + 2) * 32);
            }
        }
    }

    // epilogue: coalesce C through LDS, 32 rows at a time
#pragma unroll
    for (int h = 0; h < 2; ++h) {
        MEM_ORDER();                     // WAR: prior reads before overwrite
#pragma unroll
        for (int mtl = 0; mtl < 2; ++mtl) {
            int mt = h * 2 + mtl;
#pragma unroll
            for (int t = 0; t < 4; ++t) {
                float bb = bias[n0w + t * 16 + lr];
#pragma unroll
                for (int r = 0; r < 4; ++r)
                    Bl[(mtl * 16 + g * 4 + r) * 64 + t * 16 + lr] = acc[mt][t][r] + bb;
            }
        }
        LDS_FENCE();                     // cross-lane visibility for the reads
#pragma unroll
        for (int jj = 0; jj < 8; ++jj) {
            int rl = jj * 4 + (lane >> 4);       // local row 0..31
            f32x4 v = *(const f32x4*)&Bl[rl * 64 + (lane & 15) * 4];
            *(f32x4*)(f + (size_t)(h * 32 + rl) * NPIX + n0w + (lane & 15) * 4) = v;
        }
        MEM_ORDER();
    }
}

// --------------------------- Stencil ---------------------------
// residual = biharm + lap + f - P; reflect-1 index reflection.
#define ROWS 16
__device__ __forceinline__ int rfl(int i) {
    return i < 0 ? -i : (i > 255 ? 510 - i : i);
}
__global__ void k_stencil(const float* __restrict__ f, const float* __restrict__ P,
                          float* __restrict__ out) {
    __shared__ float fs[ROWS + 4][256];
    int x = threadIdx.x;
    int y0 = blockIdx.x * ROWS;
    int b = blockIdx.y;
    const float* fb = f + (size_t)b * NPIX;
    for (int t = 0; t < ROWS + 4; ++t) {
        int gy = rfl(y0 - 2 + t);
        fs[t][x] = fb[gy * 256 + x];
    }
    __syncthreads();

    int xm = x == 0 ? 1 : x - 1;
    int xp = x == 255 ? 254 : x + 1;

    auto lapAt = [&](int j, int i) {
        int s = j - y0 + 2;
        int sm = rfl(j - 1) - y0 + 2;
        int sp = rfl(j + 1) - y0 + 2;
        int im = i == 0 ? 1 : i - 1;
        int ip = i == 255 ? 254 : i + 1;
        float c = fs[s][i];
        return (fs[sm][i] - 2.f * c + fs[sp][i]) + (fs[s][im] - 2.f * c + fs[s][ip]);
    };

    for (int r = 0; r < ROWS; ++r) {
        int y = y0 + r;
        float lc = lapAt(y, x);
        float lym = lapAt(rfl(y - 1), x);
        float lyp = lapAt(rfl(y + 1), x);
        float lxm = lapAt(y, xm);
        float lxp = lapAt(y, xp);
        float bih = (lym - 2.f * lc + lyp) + (lxm - 2.f * lc + lxp);
        float fc = fs[r + 2][x];
        size_t idx = (size_t)b * NPIX + y * 256 + x;
        out[idx] = bih + lc + fc - P[idx];
    }
}

extern "C" void kernel_launch(void* const* d_in, const int* in_sizes, int n_in,
                              void* d_out, int out_size, void* d_ws, size_t ws_size,
                              hipStream_t stream) {
    const float* x  = (const float*)d_in[0];
    const float* P  = (const float*)d_in[1];
    const float* W1 = (const float*)d_in[2];
    const float* b1 = (const float*)d_in[3];
    const float* W2 = (const float*)d_in[4];
    const float* b2 = (const float*)d_in[5];
    const float* W3 = (const float*)d_in[6];
    const float* b3 = (const float*)d_in[7];
    const float* W4 = (const float*)d_in[8];
    const float* b4 = (const float*)d_in[9];
    float* out = (float*)d_out;

    char* ws = (char*)d_ws;
    float* h2  = (float*)(ws);                      // 64*512*4  = 128 KB
    short* h3b = (short*)(ws + (128 << 10));        // 64*1024*2 = 128 KB (bf16)
    float* f   = (float*)(ws + (256 << 10));        // 64*65536*4 = 16 MB

    k_layer12<<<dim3(512 / 16, 4), 256, 0, stream>>>(x, W1, b1, W2, b2, h2);
    k_layer3<<<dim3(1024 / 16, 4), 256, 0, stream>>>(h2, W3, b3, h3b);
    k_gemm_mfma<<<NPIX / 64, 64, 0, stream>>>(h3b, W4, b4, f);
    k_stencil<<<dim3(256 / ROWS, BATCH), 256, 0, stream>>>(f, P, out);
}

// Round 9
// 93.136 us; speedup vs baseline: 1.4746x; 1.0007x over previous
//
#include <hip/hip_runtime.h>

// MechanicsPINN: residual = EI*biharm(f) + GC*lap(f) + KC*f - P,
// f = MLP(x) 2->256->512->1024->65536, B=64, grid 256x256. All inputs fp32.
// Round 9: R8 (zero-barrier reg-staged bf16 MFMA GEMM, lgkm-only fences)
// + 2-deep register staging (RA/RB): lwrite waits a tile issued TWO steps
// earlier -> never latency-stalls; ~16KB in flight per wave continuously.

#define BATCH 64
#define NPIX 65536

typedef __attribute__((ext_vector_type(8))) short short8_t;  // bf16 x8 (4 VGPR)
typedef __attribute__((ext_vector_type(4))) float f32x4;

#define LDS_FENCE()   asm volatile("s_waitcnt lgkmcnt(0)" ::: "memory")
#define MEM_ORDER()   asm volatile("" ::: "memory")

__device__ __forceinline__ short f2bf(float x) {  // fp32 -> bf16 RNE
    unsigned u = __float_as_uint(x);
    unsigned r = (u + 0x7fffu + ((u >> 16) & 1u)) >> 16;
    return (short)r;
}

// -------- Fused layers 1+2: h2 = relu(relu(x@W1+b1) @ W2 + b2) --------
__global__ void k_layer12(const float* __restrict__ x, const float* __restrict__ W1,
                          const float* __restrict__ b1, const float* __restrict__ W2,
                          const float* __restrict__ b2, float* __restrict__ h2) {
    __shared__ float As[16][64];
    __shared__ float Ws[64][16];
    int tid = threadIdx.x;
    int tn = tid & 15, tm = tid >> 4;
    int n0 = blockIdx.x * 16, m0 = blockIdx.y * 16;
    float acc = 0.f;
    for (int k0 = 0; k0 < 256; k0 += 64) {
#pragma unroll
        for (int j = 0; j < 4; ++j) {          // build h1 16x64 tile on the fly
            int e = j * 256 + tid;
            int m = m0 + (e >> 6), kk = k0 + (e & 63);
            float v = x[m * 2 + 0] * W1[kk] + x[m * 2 + 1] * W1[256 + kk] + b1[kk];
            As[e >> 6][e & 63] = v > 0.f ? v : 0.f;
        }
#pragma unroll
        for (int j = 0; j < 4; ++j) {          // stage W2 64x16
            int e = j * 256 + tid;
            Ws[e >> 4][e & 15] = W2[(k0 + (e >> 4)) * 512 + n0 + (e & 15)];
        }
        __syncthreads();
#pragma unroll
        for (int k = 0; k < 64; ++k)
            acc += As[tm][k] * Ws[k][tn];
        __syncthreads();
    }
    acc += b2[n0 + tn];
    acc = acc > 0.f ? acc : 0.f;
    h2[(m0 + tm) * 512 + n0 + tn] = acc;
}

// -------- Layer 3: h3b(bf16) = relu(h2 @ W3 + b3), K=512, N=1024 --------
__global__ void k_layer3(const float* __restrict__ A, const float* __restrict__ Wt,
                         const float* __restrict__ bias, short* __restrict__ out_bf) {
    __shared__ float As[16][64];
    __shared__ float Ws[64][16];
    int tid = threadIdx.x;
    int tn = tid & 15, tm = tid >> 4;
    int n0 = blockIdx.x * 16, m0 = blockIdx.y * 16;
    float acc = 0.f;
    for (int k0 = 0; k0 < 512; k0 += 64) {
#pragma unroll
        for (int j = 0; j < 4; ++j) {
            int e = j * 256 + tid;
            As[e >> 6][e & 63] = A[(m0 + (e >> 6)) * 512 + k0 + (e & 63)];
        }
#pragma unroll
        for (int j = 0; j < 4; ++j) {
            int e = j * 256 + tid;
            Ws[e >> 4][e & 15] = Wt[(k0 + (e >> 4)) * 1024 + n0 + (e & 15)];
        }
        __syncthreads();
#pragma unroll
        for (int k = 0; k < 64; ++k)
            acc += As[tm][k] * Ws[k][tn];
        __syncthreads();
    }
    acc += bias[n0 + tn];
    acc = acc > 0.f ? acc : 0.f;
    out_bf[(m0 + tm) * 1024 + n0 + tn] = f2bf(acc);
}

// ---------- Main GEMM: f = h3b @ W4 + b4 (bf16 MFMA, M=64,N=65536,K=1024) ----
// One wave per block; wave owns 64 cols x all 64 m = 16 MFMA per 32-k step.
// 2-deep staging: RA/RB each hold one 32x64 fp32 tile in flight.
__global__ __launch_bounds__(64) void k_gemm_mfma(
        const short* __restrict__ A,     // h3 bf16 [64][1024]
        const float* __restrict__ W,     // W4 fp32 [1024][65536]
        const float* __restrict__ bias,  // [65536]
        float* __restrict__ f) {         // [64][65536]
    __shared__ float Bl[32 * 64];        // 8KB wave-private [k][col], swizzled
    const int lane = threadIdx.x;
    const int lr = lane & 15;
    const int g = lane >> 4;             // k-group 0..3
    const int n0w = blockIdx.x * 64;

    f32x4 acc[4][4];                     // [m-tile][n-tile]
#pragma unroll
    for (int a = 0; a < 4; ++a)
#pragma unroll
        for (int b = 0; b < 4; ++b)
            acc[a][b] = {0.f, 0.f, 0.f, 0.f};

    const short* ap = A + lr * 1024 + g * 8;

    f32x4 RA[8], RB[8];                  // 2 staging sets, 32 VGPR each
    const int kof = lane >> 4;           // k sub-row 0..3
    const int cof = (lane & 15) * 4;     // col offset

    auto gloadA = [&](int k0) {
#pragma unroll
        for (int i = 0; i < 8; ++i)
            RA[i] = *(const f32x4*)(W + (size_t)(k0 + i * 4 + kof) * NPIX + n0w + cof);
    };
    auto gloadB = [&](int k0) {
#pragma unroll
        for (int i = 0; i < 8; ++i)
            RB[i] = *(const f32x4*)(W + (size_t)(k0 + i * 4 + kof) * NPIX + n0w + cof);
    };
    // LDS element (k,col) at float idx k*64 + (col ^ ((k>>3)<<4))
    auto lwriteA = [&]() {
#pragma unroll
        for (int i = 0; i < 8; ++i) {
            int k = i * 4 + kof;
            int cc = cof ^ (((i >> 1) & 3) << 4);
            *(f32x4*)&Bl[k * 64 + cc] = RA[i];
        }
    };
    auto lwriteB = [&]() {
#pragma unroll
        for (int i = 0; i < 8; ++i) {
            int k = i * 4 + kof;
            int cc = cof ^ (((i >> 1) & 3) << 4);
            *(f32x4*)&Bl[k * 64 + cc] = RB[i];
        }
    };

    short8_t aC[4], aN[4];

    auto compute = [&](int /*s*/) {
#pragma unroll
        for (int t = 0; t < 4; ++t) {
            const int csw = (t * 16 + lr) ^ (g << 4);
            short8_t bf;
#pragma unroll
            for (int j = 0; j < 8; ++j)
                bf[j] = f2bf(Bl[(g * 8 + j) * 64 + csw]);
#pragma unroll
            for (int mt = 0; mt < 4; ++mt)
                acc[mt][t] = __builtin_amdgcn_mfma_f32_16x16x32_bf16(aC[mt], bf, acc[mt][t], 0, 0, 0);
        }
    };
    auto advanceA = [&](int s) {         // after step s: aC <- A(s+1), prefetch A(s+2)
#pragma unroll
        for (int mt = 0; mt < 4; ++mt) aC[mt] = aN[mt];
        if (s + 2 < 32) {
#pragma unroll
            for (int mt = 0; mt < 4; ++mt)
                aN[mt] = *(const short8_t*)(ap + mt * 16384 + (s + 2) * 32);
        }
    };

    // prologue: tile0 -> RA -> LDS; tile1 -> RB; tile2 -> RA; A(0),A(1)
    gloadA(0);
    gloadB(32);
#pragma unroll
    for (int mt = 0; mt < 4; ++mt)
        aC[mt] = *(const short8_t*)(ap + mt * 16384);
#pragma unroll
    for (int mt = 0; mt < 4; ++mt)
        aN[mt] = *(const short8_t*)(ap + mt * 16384 + 32);
    lwriteA();                           // waits tile0 only (counted vmcnt)
    gloadA(64);                          // tile2 immediately back in flight
    LDS_FENCE();                         // tile0 visible to all lanes

    // steady loop: even step stages from RB, odd from RA; 2-step issue slack
    for (int t2 = 0; t2 < 16; ++t2) {
        const int s0 = 2 * t2;
        // even step s0: Bl=tile s0; RB holds tile s0+1; RA holds tile s0+2
        compute(s0);
        MEM_ORDER();                     // reads before the overwrite below
        if (s0 < 31) {
            lwriteB();                   // waits tile s0+1 (issued 2 steps ago)
            LDS_FENCE();
            if (s0 < 29) gloadB((s0 + 3) * 32);
        }
        advanceA(s0);
        // odd step s1: Bl=tile s1; RA holds tile s1+1; RB holds tile s1+2
        const int s1 = s0 + 1;
        compute(s1);
        MEM_ORDER();
        if (s1 < 31) {
            lwriteA();
            LDS_FENCE();
            if (s1 < 29) gloadA((s1 + 3) * 32);
        }
        advanceA(s1);
    }

    // epilogue: coalesce C through LDS, 32 rows at a time
#pragma unroll
    for (int h = 0; h < 2; ++h) {
        MEM_ORDER();                     // WAR: prior reads before overwrite
#pragma unroll
        for (int mtl = 0; mtl < 2; ++mtl) {
            int mt = h * 2 + mtl;
#pragma unroll
            for (int t = 0; t < 4; ++t) {
                float bb = bias[n0w + t * 16 + lr];
#pragma unroll
                for (int r = 0; r < 4; ++r)
                    Bl[(mtl * 16 + g * 4 + r) * 64 + t * 16 + lr] = acc[mt][t][r] + bb;
            }
        }
        LDS_FENCE();                     // cross-lane visibility for the reads
#pragma unroll
        for (int jj = 0; jj < 8; ++jj) {
            int rl = jj * 4 + kof;       // local row 0..31
            f32x4 v = *(const f32x4*)&Bl[rl * 64 + cof];
            *(f32x4*)(f + (size_t)(h * 32 + rl) * NPIX + n0w + cof) = v;
        }
        MEM_ORDER();
    }
}

// --------------------------- Stencil ---------------------------
// residual = biharm + lap + f - P; reflect-1 index reflection.
#define ROWS 16
__device__ __forceinline__ int rfl(int i) {
    return i < 0 ? -i : (i > 255 ? 510 - i : i);
}
__global__ void k_stencil(const float* __restrict__ f, const float* __restrict__ P,
                          float* __restrict__ out) {
    __shared__ float fs[ROWS + 4][256];
    int x = threadIdx.x;
    int y0 = blockIdx.x * ROWS;
    int b = blockIdx.y;
    const float* fb = f + (size_t)b * NPIX;
    for (int t = 0; t < ROWS + 4; ++t) {
        int gy = rfl(y0 - 2 + t);
        fs[t][x] = fb[gy * 256 + x];
    }
    __syncthreads();

    int xm = x == 0 ? 1 : x - 1;
    int xp = x == 255 ? 254 : x + 1;

    auto lapAt = [&](int j, int i) {
        int s = j - y0 + 2;
        int sm = rfl(j - 1) - y0 + 2;
        int sp = rfl(j + 1) - y0 + 2;
        int im = i == 0 ? 1 : i - 1;
        int ip = i == 255 ? 254 : i + 1;
        float c = fs[s][i];
        return (fs[sm][i] - 2.f * c + fs[sp][i]) + (fs[s][im] - 2.f * c + fs[s][ip]);
    };

    for (int r = 0; r < ROWS; ++r) {
        int y = y0 + r;
        float lc = lapAt(y, x);
        float lym = lapAt(rfl(y - 1), x);
        float lyp = lapAt(rfl(y + 1), x);
        float lxm = lapAt(y, xm);
        float lxp = lapAt(y, xp);
        float bih = (lym - 2.f * lc + lyp) + (lxm - 2.f * lc + lxp);
        float fc = fs[r + 2][x];
        size_t idx = (size_t)b * NPIX + y * 256 + x;
        out[idx] = bih + lc + fc - P[idx];
    }
}

extern "C" void kernel_launch(void* const* d_in, const int* in_sizes, int n_in,
                              void* d_out, int out_size, void* d_ws, size_t ws_size,
                              hipStream_t stream) {
    const float* x  = (const float*)d_in[0];
    const float* P  = (const float*)d_in[1];
    const float* W1 = (const float*)d_in[2];
    const float* b1 = (const float*)d_in[3];
    const float* W2 = (const float*)d_in[4];
    const float* b2 = (const float*)d_in[5];
    const float* W3 = (const float*)d_in[6];
    const float* b3 = (const float*)d_in[7];
    const float* W4 = (const float*)d_in[8];
    const float* b4 = (const float*)d_in[9];
    float* out = (float*)d_out;

    char* ws = (char*)d_ws;
    float* h2  = (float*)(ws);                      // 64*512*4  = 128 KB
    short* h3b = (short*)(ws + (128 << 10));        // 64*1024*2 = 128 KB (bf16)
    float* f   = (float*)(ws + (256 << 10));        // 64*65536*4 = 16 MB

    k_layer12<<<dim3(512 / 16, 4), 256, 0, stream>>>(x, W1, b1, W2, b2, h2);
    k_layer3<<<dim3(1024 / 16, 4), 256, 0, stream>>>(h2, W3, b3, h3b);
    k_gemm_mfma<<<NPIX / 64, 64, 0, stream>>>(h3b, W4, b4, f);
    k_stencil<<<dim3(256 / ROWS, BATCH), 256, 0, stream>>>(f, P, out);
}